// Round 5
// baseline (3671.674 us; speedup 1.0000x reference)
//
#include <hip/hip_runtime.h>

typedef unsigned short u16;
typedef unsigned int   u32;
typedef unsigned long long u64;
typedef __attribute__((ext_vector_type(8))) short bf16x8;
typedef __attribute__((ext_vector_type(16))) float f32x16;
typedef __attribute__((ext_vector_type(4))) float f32x4;
typedef __attribute__((ext_vector_type(4))) u32 u32x4;

#define T_SEQ 300

// workspace layout (bytes) — all offsets 16B-aligned
#define OFF_WP   0u            // packed A-frag weights bf16: 256 jp * 42 kk * 64 lanes * 16B = 11,010,048
#define OFF_BP   11010048u     // packed bias f32 [512 j][16 g] = 32,768
#define OFF_XB   11042816u     // x bf16 K-slot layout: 300*128*192*2 = 14,745,600
#define OFF_H    25788416u     // h arena bf16: 301 * 128*512 * 2B = 39,452,672
#define OFF_FL   65241088u     // flags[128] = [bq 4][32 jgh]

__device__ __forceinline__ float bf2f(u16 u){ union { u32 u; float f; } v; v.u = ((u32)u) << 16; return v.f; }
__device__ __forceinline__ u16 f2bf(float f){
  union { float f; u32 u; } v; v.f = f;
  u32 r = v.u + 0x7fffu + ((v.u >> 16) & 1u);
  return (u16)(r >> 16);
}
__device__ __forceinline__ float sigf(float x){ return 1.f / (1.f + __expf(-x)); }
__device__ __forceinline__ float tanh_f(float x){ return 1.f - 2.f / (1.f + __expf(2.f * x)); }

// ---------------------------------------------------------------------------
// prep: pack fp32 weights into 32x32x16 MFMA *A-operand* fragments (weights on
// the M side; gates in M). M-row m -> (jj=(m>>2)&1, g=(m&3)+4*(m>>3)); with the
// C/D layout row=(reg&3)+8*(reg>>2)+4*(lane>>5) this makes acc[reg]=gate reg
// for j=jp*2+(lane>>5) per lane. A[m][k]: m=lane&31, k=kk*16+(lane>>5)*8+i
// (same per-lane k-convention used for the B pack — a uniform k-permutation
// cancels between operands). K-space (672): [0,512)=hidden, [512,672)=
// 5 parts * 32 slots (slot (p,cc,ii): d=cc*8+ii for cc<3; cc==3: ii<2 -> ZERO
// weight (data dups x[22],x[23]), ii>=2 -> d=22+ii). g<15: part p=g/3, type
// g%3 (own part only); g==15: shared o-gate (Who/Wxo, all parts).
// Also: bias pack [j][16], zero h[0], reset flags.
// ---------------------------------------------------------------------------
__global__ void prep(const float* __restrict__ Wx, const float* __restrict__ Wh,
                     const float* __restrict__ bg, const float* __restrict__ Wxo,
                     const float* __restrict__ Who, const float* __restrict__ bo,
                     u16* __restrict__ Wp, float* __restrict__ bpack,
                     u16* __restrict__ h0, int* __restrict__ flags)
{
  int w = blockIdx.x * 256 + threadIdx.x;     // 0 .. 688127 = 256 jp * 42 kk * 64 lanes

  if (w < 8192) {
    u32x4 z = {0u, 0u, 0u, 0u};
    ((u32x4*)h0)[w] = z;                      // zero h[0] (128*512 bf16)
    int j = w >> 4, g = w & 15;
    float bv;
    if (g < 15) { int p = g / 3, t3 = g - p * 3; bv = bg[p * 1536 + t3 * 512 + j]; }
    else bv = bo[j];
    bpack[w] = bv;
  }
  if (w < 128) flags[w] = 0;

  int lane = w & 63, rem = w >> 6;
  int kk = rem % 42, jp = rem / 42;           // jp 0..255
  int m = lane & 31, hi = lane >> 5;
  int jj = (m >> 2) & 1, g = (m & 3) + 4 * (m >> 3);
  int j = jp * 2 + jj;
  union { u16 s[8]; u32x4 v; } o;
  #pragma unroll
  for (int i = 0; i < 8; ++i) {
    int k = kk * 16 + hi * 8 + i;
    float val = 0.f;
    if (g < 15) {
      int p = g / 3, t3 = g - p * 3, col = t3 * 512 + j;
      if (k < 512) val = Wh[(p * 512 + k) * 1536 + col];
      else {
        int s = k - 512, px = s >> 5, cc = (s >> 3) & 3, ii = s & 7;
        int d = (cc < 3) ? cc * 8 + ii : ((ii < 2) ? -1 : 22 + ii);
        if (px == p && d >= 0) val = Wx[(p * 30 + d) * 1536 + col];
      }
    } else {
      if (k < 512) val = Who[k * 512 + j];
      else {
        int s = k - 512, px = s >> 5, cc = (s >> 3) & 3, ii = s & 7;
        int d = (cc < 3) ? cc * 8 + ii : ((ii < 2) ? -1 : 22 + ii);
        if (d >= 0) val = Wxo[(px * 30 + d) * 512 + j];
      }
    }
    o.s[i] = f2bf(val);
  }
  *(u32x4*)(Wp + ((size_t)(jp * 42 + kk) * 64 + lane) * 8) = o.v;
}

// ---------------------------------------------------------------------------
// prep_x: fp32 x [5][128][300][30] -> bf16 xb[t][bglob][slot] (slot 0..191,
// slots 160..191 zero pad). One thread = one 8-slot chunk (16B store).
// ---------------------------------------------------------------------------
__global__ void prep_x(const float* __restrict__ x, u16* __restrict__ xb)
{
  int w = blockIdx.x * 256 + threadIdx.x;     // 0 .. 921599
  int cx = w % 24, rem = w / 24;
  int bglob = rem % 128, t = rem / 128;
  union { u16 s[8]; u32x4 v; } o;
  int s0 = cx << 3;
  if (s0 >= 160) {
    u32x4 z = {0u, 0u, 0u, 0u}; o.v = z;
  } else {
    int p = s0 >> 5, cc = (s0 >> 3) & 3;
    const float* row = x + ((size_t)(p * 128 + bglob) * 300 + t) * 30;
    #pragma unroll
    for (int i = 0; i < 8; ++i) {
      int d = (cc < 3) ? cc * 8 + i : 22 + i;
      o.s[i] = f2bf(row[d]);
    }
  }
  *(u32x4*)(xb + (size_t)w * 8) = o.v;
}

// Distributed readiness: two lanes poll each of the 32 flags of one batch
// quarter (relaxed agent loads, single-issue — round-1 proven form).
__device__ __forceinline__ void wait_flags32(const int* f, int t)
{
  int l = threadIdx.x & 31;
  for (;;) {
    int v = __hip_atomic_load(&f[l], __ATOMIC_RELAXED, __HIP_MEMORY_SCOPE_AGENT);
    if (__all(v >= t)) break;
  }
}

// ---------------------------------------------------------------------------
// Persistent part-LSTM, gate-in-lane formulation — round-1 skeleton with
// DIRECT global->VGPR B-fragments (no Xsh/Hsh staging).
// 128 blocks x 512 threads. Block = (bq=idx&3: batch quarter) x (jgh=idx>>2:
// 16 hidden cols). Wave = one 32x32x16 MFMA tile chain, jp = jgh*8 + wv.
//
// Key change vs round 1: with hall layout [t][b:128][j:512] and xb layout
// [t][b:128][slot:192], a wave's B-fragment for MFMA step kk is 16B/lane at
// (row n) base + kk*32 bytes — ONE base address + compile-time offset. So
// B-operands are loaded straight from global (L1/L2-shared across the 8
// waves, which all read the same 32 rows; same-XCD blocks share the same
// quarter's lines via bq=idx&3 co-location). This removes both LDS staging
// round-trips, 2 of the 4 per-step barriers, and all staging bank conflicts.
// Per step: 10 x-loads+MFMAs (no h dep, absorbs jitter) -> wave0 polls ->
// barrier -> 32 h-loads+MFMAs (compiler-pipelined) -> elementwise -> hbuf
// transpose -> barrier -> wave 0 publishes (16B/lane stores + lane-local
// vmcnt drain + flag).
// ---------------------------------------------------------------------------
__global__ void __launch_bounds__(512, 2)
plstm(const u16* __restrict__ xb, const u16* __restrict__ Wp,
      const float* __restrict__ bpack, u16* hall, int* flags,
      const float* __restrict__ fcw, const float* __restrict__ fcb,
      float* __restrict__ out)
{
  __shared__ __align__(16) u16 hbuf[32 * 16];   // 1 KB: h publish staging
  __shared__ __align__(16) float fsh[640];      // classifier scratch

  const int tid  = threadIdx.x;
  const int lane = tid & 63;
  const int wv   = tid >> 6;          // 8 waves
  const int n    = lane & 31;         // batch row within quarter
  const int hi   = lane >> 5;         // k-half / j-parity
  const int bq   = blockIdx.x & 3;    // 0..3  (XCD co-location remap)
  const int jgh  = blockIdx.x >> 2;   // 0..31 (16 j each)
  const int jp   = jgh * 8 + wv;      // j-pair 0..255
  const int j    = jp * 2 + hi;       // this lane's hidden col
  int* myflags = flags + bq * 32;

  // resident A-fragments (weights), 42 ksteps x 4 regs (loaded once)
  bf16x8 afr[42];
  {
    const u16* wpb = Wp + ((size_t)jp * 42 * 64 + lane) * 8;
    #pragma unroll
    for (int kk = 0; kk < 42; ++kk)
      afr[kk] = *(const bf16x8*)(wpb + kk * 512);
  }
  float bias[16];
  #pragma unroll
  for (int i = 0; i < 4; ++i)
    *(f32x4*)(bias + i * 4) = *(const f32x4*)(bpack + j * 16 + i * 4);

  float cst[5] = {0.f, 0.f, 0.f, 0.f, 0.f};

  // per-lane B-fragment base rows (advance by constant stride per step)
  const u16* xrow = xb + ((size_t)(bq * 32 + n)) * 192 + hi * 8;
  const u16* hrow = hall + ((size_t)(bq * 32 + n)) * 512 + hi * 8;

  for (int t = 0; t < T_SEQ; ++t) {
    // ---- K-loop, x part: direct 16B B-frag loads (no h dependency;
    // latency absorbed by the flag wait that follows) ----
    f32x16 acc;
    #pragma unroll
    for (int i = 0; i < 16; ++i) acc[i] = 0.f;
    {
      const u16* xr = xrow + (size_t)t * (128 * 192);
      #pragma unroll
      for (int kx = 0; kx < 10; ++kx) {
        bf16x8 bf = *(const bf16x8*)(xr + kx * 16);   // byte offset kx*32
        acc = __builtin_amdgcn_mfma_f32_32x32x16_bf16(afr[32 + kx], bf, acc, 0, 0, 0);
      }
    }

    // ---- wave 0 polls own-quarter flags; barrier release ----
    if (wv == 0) wait_flags32(myflags, t);
    __syncthreads();                     // (A) release + hbuf read/write fence

    // ---- K-loop, hidden part: direct 16B B-frag loads, compiler-pipelined
    // against the MFMA chain (one base reg + offset:kk*32 per load) ----
    {
      const u16* hr = hrow + (size_t)t * 65536;
      #pragma unroll
      for (int kk = 0; kk < 32; ++kk) {
        bf16x8 bf = *(const bf16x8*)(hr + kk * 16);   // byte offset kk*32
        acc = __builtin_amdgcn_mfma_f32_32x32x16_bf16(afr[kk], bf, acc, 0, 0, 0);
      }
    }

    // ---- per-lane elementwise: acc[g] = gate g for (j, b) ----
    float cs = 0.f;
    #pragma unroll
    for (int p = 0; p < 5; ++p) {
      float iv = acc[p * 3 + 0] + bias[p * 3 + 0];
      float fv = acc[p * 3 + 1] + bias[p * 3 + 1];
      float gv = acc[p * 3 + 2] + bias[p * 3 + 2];
      cst[p] = sigf(fv) * cst[p] + sigf(iv) * tanh_f(gv);
      cs += cst[p];
    }
    float hv = sigf(acc[15] + bias[15]) * tanh_f(cs);

    // ---- publish h(t+1): LDS transpose -> 16B agent-scope stores by wave 0;
    // lane-local vmcnt drain; flag. Other waves fall through to next step's
    // x loads/MFMAs (no LDS involved); wave 0's hbuf reads complete before
    // it reaches the next barrier (A), and hbuf is rewritten only after (A).
    hbuf[(n << 4) + (wv << 1) + hi] = f2bf(hv);
    __syncthreads();                     // (B) hbuf written -> wave 0 may read
    if (tid < 64) {
      int row = tid >> 1, half = tid & 1;
      const u16* src = hbuf + (row << 4) + (half << 3);
      u64 v0 = *(const u64*)(src);
      u64 v1 = *(const u64*)(src + 4);
      u64* dst = (u64*)(hall + (size_t)(t + 1) * 65536
                        + (size_t)(bq * 32 + row) * 512 + (jgh << 4) + (half << 3));
      __hip_atomic_store(dst,     v0, __ATOMIC_RELAXED, __HIP_MEMORY_SCOPE_AGENT);
      __hip_atomic_store(dst + 1, v1, __ATOMIC_RELAXED, __HIP_MEMORY_SCOPE_AGENT);
      asm volatile("s_waitcnt vmcnt(0)" ::: "memory");   // wave-0-local drain
      if (tid == 0)
        __hip_atomic_store(&myflags[jgh], t + 1, __ATOMIC_RELAXED, __HIP_MEMORY_SCOPE_AGENT);
    }
  }

  // ---- classifier + log_softmax: blocks 0..63 do 2 batch rows each ----
  if (blockIdx.x >= 64) return;
  for (;;) {
    int v0 = __hip_atomic_load(&flags[lane],      __ATOMIC_RELAXED, __HIP_MEMORY_SCOPE_AGENT);
    int v1 = __hip_atomic_load(&flags[64 + lane], __ATOMIC_RELAXED, __HIP_MEMORY_SCOPE_AGENT);
    if (__all(min(v0, v1) >= T_SEQ)) break;
  }
  __syncthreads();
  const u16* hT = hall + (size_t)T_SEQ * 65536;
  for (int r = 0; r < 2; ++r) {
    int row = blockIdx.x * 2 + r;
    int ks = tid >> 6, c = tid & 63;      // 8 K-slices of 64
    float s = 0.f;
    if (c < 60) {
      const u16* hr = hT + row * 512 + ks * 64;
      const float* wr = fcw + (size_t)(ks * 64) * 60 + c;
      #pragma unroll 8
      for (int k = 0; k < 64; ++k) s += bf2f(hr[k]) * wr[k * 60];
    }
    __syncthreads();
    fsh[ks * 64 + c] = s;
    __syncthreads();
    if (tid < 60) {
      float lg = fcb[tid];
      #pragma unroll
      for (int i = 0; i < 8; ++i) lg += fsh[i * 64 + tid];
      fsh[512 + tid] = lg;
    }
    __syncthreads();
    if (tid == 0) {
      float mx = -1e30f;
      for (int i = 0; i < 60; ++i) mx = fmaxf(mx, fsh[512 + i]);
      float sm = 0.f;
      for (int i = 0; i < 60; ++i) sm += __expf(fsh[512 + i] - mx);
      fsh[576] = mx + __logf(sm);
    }
    __syncthreads();
    if (tid < 60) out[row * 60 + tid] = fsh[512 + tid] - fsh[576];
    __syncthreads();
  }
}

extern "C" void kernel_launch(void* const* d_in, const int* in_sizes, int n_in,
                              void* d_out, int out_size, void* d_ws, size_t ws_size,
                              hipStream_t stream)
{
  const float* xin = (const float*)d_in[0];   // [5][128][300][30]
  const float* Wx  = (const float*)d_in[1];   // [5][30][1536]
  const float* Wh  = (const float*)d_in[2];   // [5][512][1536]
  const float* bg  = (const float*)d_in[3];   // [5][1536]
  const float* Wxo = (const float*)d_in[4];   // [150][512]
  const float* Who = (const float*)d_in[5];   // [512][512]
  const float* bo  = (const float*)d_in[6];   // [512]
  const float* fcw = (const float*)d_in[7];   // [512][60]
  const float* fcb = (const float*)d_in[8];   // [60]
  float* out = (float*)d_out;                 // [128][60]

  char* ws = (char*)d_ws;
  u16*   Wp    = (u16*)(ws + OFF_WP);
  float* bpack = (float*)(ws + OFF_BP);
  u16*   xb    = (u16*)(ws + OFF_XB);
  u16*   hall  = (u16*)(ws + OFF_H);
  int*   flags = (int*)(ws + OFF_FL);

  hipLaunchKernelGGL(prep, dim3(2688), dim3(256), 0, stream,
                     Wx, Wh, bg, Wxo, Who, bo, Wp, bpack, hall, flags);
  hipLaunchKernelGGL(prep_x, dim3(3600), dim3(256), 0, stream, xin, xb);

  void* args[] = { (void*)&xb, (void*)&Wp, (void*)&bpack, (void*)&hall,
                   (void*)&flags, (void*)&fcw, (void*)&fcb, (void*)&out };
  hipLaunchCooperativeKernel((void*)plstm, dim3(128), dim3(512), args, 0, stream);
}

// Round 6
// 1489.422 us; speedup vs baseline: 2.4652x; 2.4652x over previous
//
#include <hip/hip_runtime.h>

typedef unsigned short u16;
typedef unsigned int   u32;
typedef unsigned long long u64;
typedef __attribute__((ext_vector_type(8))) short bf16x8;
typedef __attribute__((ext_vector_type(16))) float f32x16;
typedef __attribute__((ext_vector_type(4))) float f32x4;
typedef __attribute__((ext_vector_type(4))) u32 u32x4;

#define T_SEQ 300

// workspace layout (bytes) — all offsets 16B-aligned
#define OFF_WP   0u            // packed A-frag weights bf16: 256 jp * 42 kk * 64 lanes * 16B = 11,010,048
#define OFF_BP   11010048u     // packed bias f32 [512 j][16 g] = 32,768
#define OFF_XB   11042816u     // x bf16 K-slot layout: 300*128*192*2 = 14,745,600
#define OFF_H    25788416u     // h arena bf16: 301 * [bq 4][jgh 32][n 32][jl 16] * 2B = 39,452,672
#define OFF_FL   65241088u     // flags[128 * 32] — ONE 128B line per flag (false-sharing fix)

__device__ __forceinline__ float bf2f(u16 u){ union { u32 u; float f; } v; v.u = ((u32)u) << 16; return v.f; }
__device__ __forceinline__ u16 f2bf(float f){
  union { float f; u32 u; } v; v.f = f;
  u32 r = v.u + 0x7fffu + ((v.u >> 16) & 1u);
  return (u16)(r >> 16);
}
__device__ __forceinline__ float sigf(float x){ return 1.f / (1.f + __expf(-x)); }
__device__ __forceinline__ float tanh_f(float x){ return 1.f - 2.f / (1.f + __expf(2.f * x)); }

// ---------------------------------------------------------------------------
// prep: pack fp32 weights into 32x32x16 MFMA *A-operand* fragments (weights on
// the M side; gates in M). M-row m -> (jj=(m>>2)&1, g=(m&3)+4*(m>>3)); with the
// C/D layout row=(reg&3)+8*(reg>>2)+4*(lane>>5) this makes acc[reg]=gate reg
// for j=jp*2+(lane>>5) per lane. A[m][k]: m=lane&31, k=kk*16+(lane>>5)*8+i
// (same per-lane k-convention used for the B pack — a uniform k-permutation
// cancels between operands). K-space (672): [0,512)=hidden, [512,672)=
// 5 parts * 32 slots (slot (p,cc,ii): d=cc*8+ii for cc<3; cc==3: ii<2 -> ZERO
// weight (data dups x[22],x[23]), ii>=2 -> d=22+ii). g<15: part p=g/3, type
// g%3 (own part only); g==15: shared o-gate (Who/Wxo, all parts).
// Also: bias pack [j][16], zero h[0], reset flags (padded, 4096 ints).
// ---------------------------------------------------------------------------
__global__ void prep(const float* __restrict__ Wx, const float* __restrict__ Wh,
                     const float* __restrict__ bg, const float* __restrict__ Wxo,
                     const float* __restrict__ Who, const float* __restrict__ bo,
                     u16* __restrict__ Wp, float* __restrict__ bpack,
                     u16* __restrict__ h0, int* __restrict__ flags)
{
  int w = blockIdx.x * 256 + threadIdx.x;     // 0 .. 688127 = 256 jp * 42 kk * 64 lanes

  if (w < 8192) {
    u32x4 z = {0u, 0u, 0u, 0u};
    ((u32x4*)h0)[w] = z;                      // zero h[0] (128*512 bf16)
    int j = w >> 4, g = w & 15;
    float bv;
    if (g < 15) { int p = g / 3, t3 = g - p * 3; bv = bg[p * 1536 + t3 * 512 + j]; }
    else bv = bo[j];
    bpack[w] = bv;
  }
  if (w < 4096) flags[w] = 0;                 // 128 flags * 32-int (128B) stride

  int lane = w & 63, rem = w >> 6;
  int kk = rem % 42, jp = rem / 42;           // jp 0..255
  int m = lane & 31, hi = lane >> 5;
  int jj = (m >> 2) & 1, g = (m & 3) + 4 * (m >> 3);
  int j = jp * 2 + jj;
  union { u16 s[8]; u32x4 v; } o;
  #pragma unroll
  for (int i = 0; i < 8; ++i) {
    int k = kk * 16 + hi * 8 + i;
    float val = 0.f;
    if (g < 15) {
      int p = g / 3, t3 = g - p * 3, col = t3 * 512 + j;
      if (k < 512) val = Wh[(p * 512 + k) * 1536 + col];
      else {
        int s = k - 512, px = s >> 5, cc = (s >> 3) & 3, ii = s & 7;
        int d = (cc < 3) ? cc * 8 + ii : ((ii < 2) ? -1 : 22 + ii);
        if (px == p && d >= 0) val = Wx[(p * 30 + d) * 1536 + col];
      }
    } else {
      if (k < 512) val = Who[k * 512 + j];
      else {
        int s = k - 512, px = s >> 5, cc = (s >> 3) & 3, ii = s & 7;
        int d = (cc < 3) ? cc * 8 + ii : ((ii < 2) ? -1 : 22 + ii);
        if (d >= 0) val = Wxo[(px * 30 + d) * 512 + j];
      }
    }
    o.s[i] = f2bf(val);
  }
  *(u32x4*)(Wp + ((size_t)(jp * 42 + kk) * 64 + lane) * 8) = o.v;
}

// ---------------------------------------------------------------------------
// prep_x: fp32 x [5][128][300][30] -> bf16 xb[t][bglob][slot] (slot 0..191,
// slots 160..191 zero pad). One thread = one 8-slot chunk (16B store).
// ---------------------------------------------------------------------------
__global__ void prep_x(const float* __restrict__ x, u16* __restrict__ xb)
{
  int w = blockIdx.x * 256 + threadIdx.x;     // 0 .. 921599
  int cx = w % 24, rem = w / 24;
  int bglob = rem % 128, t = rem / 128;
  union { u16 s[8]; u32x4 v; } o;
  int s0 = cx << 3;
  if (s0 >= 160) {
    u32x4 z = {0u, 0u, 0u, 0u}; o.v = z;
  } else {
    int p = s0 >> 5, cc = (s0 >> 3) & 3;
    const float* row = x + ((size_t)(p * 128 + bglob) * 300 + t) * 30;
    #pragma unroll
    for (int i = 0; i < 8; ++i) {
      int d = (cc < 3) ? cc * 8 + i : 22 + i;
      o.s[i] = f2bf(row[d]);
    }
  }
  *(u32x4*)(xb + (size_t)w * 8) = o.v;
}

// Distributed readiness: two lanes poll each of the 32 flags of one batch
// quarter. Each flag owns a full 128B line -> 32 parallel line reads, no
// producer-side line ping-pong.
__device__ __forceinline__ void wait_flags32(const int* f, int t)
{
  int l = threadIdx.x & 31;
  for (;;) {
    int v = __hip_atomic_load(&f[l * 32], __ATOMIC_RELAXED, __HIP_MEMORY_SCOPE_AGENT);
    if (__all(v >= t)) break;
  }
}

// ---------------------------------------------------------------------------
// Persistent part-LSTM, gate-in-lane formulation — round-1 skeleton with
// line-exclusive sync structures.
// 128 blocks x 512 threads. Block = (bq=idx&3: batch quarter, XCD co-located)
// x (jgh=idx>>2: 16 hidden cols). Wave = one 32x32x16 MFMA tile chain,
// jp = jgh*8 + wv. Weights resident in VGPRs (loaded once).
//
// Sync-structure changes vs round 1 (the only changes):
//  * flags: one 128B line per flag -> producer flag stores never contend for
//    a line; poll reads 32 lines in parallel.
//  * hall layout [t][bq:4][jgh:32][n:32][jl:16]: each producer's 1KB publish
//    is 8 exclusively-owned lines (was 32 lines shared 4-way). The consumer
//    stage source address is LINEAR in the staging index (base + idx*16B) ->
//    fully coalesced, and logical chunk cx == round-1's c, so the LDS
//    swizzle + MFMA loops are unchanged.
// ---------------------------------------------------------------------------
__global__ void __launch_bounds__(512, 2)
plstm(const u16* __restrict__ xb, const u16* __restrict__ Wp,
      const float* __restrict__ bpack, u16* hall, int* flags,
      const float* __restrict__ fcw, const float* __restrict__ fcb,
      float* __restrict__ out)
{
  __shared__ __align__(16) u16 Hsh[32 * 512];   // 32 KB: h rows [n][64 chunks] (xor-swizzled)
  __shared__ __align__(16) u16 Xsh[32 * 256];   // 16 KB: x rows [n][32 chunks] (xor-swizzled)
  __shared__ __align__(16) u16 hbuf[32 * 16];   // 1 KB: h publish staging [n][jl]

  const int tid  = threadIdx.x;
  const int lane = tid & 63;
  const int wv   = tid >> 6;          // 8 waves
  const int n    = lane & 31;         // batch row within quarter
  const int hi   = lane >> 5;         // k-half / j-parity
  const int bq   = blockIdx.x & 3;    // 0..3  (XCD co-location remap)
  const int jgh  = blockIdx.x >> 2;   // 0..31 (16 j each)
  const int jp   = jgh * 8 + wv;      // j-pair 0..255
  const int j    = jp * 2 + hi;       // this lane's hidden col
  int* myflags = flags + bq * 1024;   // 32 flags * 32-int stride

  // resident A-fragments (weights), 42 ksteps x 4 VGPRs
  bf16x8 afr[42];
  {
    const u16* wpb = Wp + ((size_t)jp * 42 * 64 + lane) * 8;
    #pragma unroll
    for (int kk = 0; kk < 42; ++kk)
      afr[kk] = *(const bf16x8*)(wpb + kk * 512);
  }
  float bias[16];
  #pragma unroll
  for (int i = 0; i < 4; ++i)
    *(f32x4*)(bias + i * 4) = *(const f32x4*)(bpack + j * 16 + i * 4);

  float cst[5] = {0.f, 0.f, 0.f, 0.f, 0.f};

  for (int t = 0; t < T_SEQ; ++t) {
    // ---- stage x[t] rows (own quarter) into LDS, chunk-XOR swizzle ----
    {
      const u16* xsrc = xb + (size_t)(t * 128 + bq * 32) * 192;
      #pragma unroll
      for (int i = 0; i < 2; ++i) {
        int c = tid + (i << 9);           // 0..1023, valid < 768 = 32 rows * 24 chunks
        if (c < 768) {
          int b = c / 24, cx = c - b * 24;
          u32x4 v = *(const u32x4*)(xsrc + b * 192 + (cx << 3));
          *(u32x4*)(Xsh + (b << 8) + (((cx ^ b) & 31) << 3)) = v;
        }
      }
    }
    __syncthreads();

    f32x16 acc;
    #pragma unroll
    for (int i = 0; i < 16; ++i) acc[i] = 0.f;

    // ---- K-loop, x part (no h dependency — absorbs inter-block jitter) ----
    #pragma unroll
    for (int kx = 0; kx < 10; ++kx) {
      int c = kx * 2 + hi;                // chunk 0..19
      bf16x8 bf = *(const bf16x8*)(Xsh + (n << 8) + (((c ^ n) & 31) << 3));
      acc = __builtin_amdgcn_mfma_f32_32x32x16_bf16(afr[32 + kx], bf, acc, 0, 0, 0);
    }

    // ---- wave 0 polls own-quarter flags; barrier release ----
    if (wv == 0) wait_flags32(myflags, t);
    __syncthreads();

    // ---- stage h[t] (own quarter, block-major source, LINEAR in idx) into
    // LDS with the round-1 swizzle. idx rotated by jgh*64 so each block
    // starts at its own output's chunk group (L2-local first).
    {
      const u16* hsrc = hall + (size_t)t * 65536 + bq * 16384;
      #pragma unroll
      for (int i = 0; i < 4; ++i) {
        int idx = (tid + (i << 9) + (jgh << 6)) & 2047;  // 2048 chunks of 16B
        u32x4 v = *(const u32x4*)(hsrc + idx * 8);
        int nn = (idx >> 1) & 31;                        // batch row
        int cx = ((idx >> 6) << 1) | (idx & 1);          // logical chunk == round-1 c
        int phys = (cx & 32) | ((cx ^ nn) & 31);
        *(u32x4*)(Hsh + (nn << 9) + (phys << 3)) = v;
      }
    }
    __syncthreads();

    // ---- K-loop, hidden part (unchanged from round 1) ----
    #pragma unroll
    for (int kk = 0; kk < 32; ++kk) {
      int c = kk * 2 + hi;                // chunk 0..63
      int phys = (c & 32) | ((c ^ n) & 31);
      bf16x8 bf = *(const bf16x8*)(Hsh + (n << 9) + (phys << 3));
      acc = __builtin_amdgcn_mfma_f32_32x32x16_bf16(afr[kk], bf, acc, 0, 0, 0);
    }

    // ---- per-lane elementwise: acc[g] = gate g for (j, b) ----
    float cs = 0.f;
    #pragma unroll
    for (int p = 0; p < 5; ++p) {
      float iv = acc[p * 3 + 0] + bias[p * 3 + 0];
      float fv = acc[p * 3 + 1] + bias[p * 3 + 1];
      float gv = acc[p * 3 + 2] + bias[p * 3 + 2];
      cst[p] = sigf(fv) * cst[p] + sigf(iv) * tanh_f(gv);
      cs += cst[p];
    }
    float hv = sigf(acc[15] + bias[15]) * tanh_f(cs);

    // ---- publish h(t+1): LDS transpose -> contiguous 1KB (8 exclusive
    // lines) of agent-scope stores by wave 0; lane-local vmcnt drain; flag.
    hbuf[(n << 4) + (wv << 1) + hi] = f2bf(hv);
    __syncthreads();
    if (tid < 64) {
      const u16* src = hbuf + tid * 8;    // 16B per lane, linear
      u64 v0 = *(const u64*)(src);
      u64 v1 = *(const u64*)(src + 4);
      u64* dst = (u64*)(hall + (size_t)(t + 1) * 65536 + bq * 16384
                        + jgh * 512 + tid * 8);
      __hip_atomic_store(dst,     v0, __ATOMIC_RELAXED, __HIP_MEMORY_SCOPE_AGENT);
      __hip_atomic_store(dst + 1, v1, __ATOMIC_RELAXED, __HIP_MEMORY_SCOPE_AGENT);
      asm volatile("s_waitcnt vmcnt(0)" ::: "memory");   // wave-0-local drain
      if (tid == 0)
        __hip_atomic_store(&myflags[jgh * 32], t + 1, __ATOMIC_RELAXED, __HIP_MEMORY_SCOPE_AGENT);
    }
  }

  // ---- classifier + log_softmax: blocks 0..63 do 2 batch rows each ----
  if (blockIdx.x >= 64) return;
  for (;;) {
    int v0 = __hip_atomic_load(&flags[lane * 32],        __ATOMIC_RELAXED, __HIP_MEMORY_SCOPE_AGENT);
    int v1 = __hip_atomic_load(&flags[2048 + lane * 32], __ATOMIC_RELAXED, __HIP_MEMORY_SCOPE_AGENT);
    if (__all(min(v0, v1) >= T_SEQ)) break;
  }
  __syncthreads();
  float* fsh = (float*)Hsh;
  const u16* hT = hall + (size_t)T_SEQ * 65536;
  for (int r = 0; r < 2; ++r) {
    int row = blockIdx.x * 2 + r;
    int ks = tid >> 6, c = tid & 63;      // 8 K-slices of 64
    float s = 0.f;
    if (c < 60) {
      // hall element (row, j) -> [row>>5][j>>4][row&31][j&15]
      const u16* hb = hT + (row >> 5) * 16384 + (row & 31) * 16;
      const float* wr = fcw + (size_t)(ks * 64) * 60 + c;
      #pragma unroll 8
      for (int k = 0; k < 64; ++k)
        s += bf2f(hb[(ks * 4 + (k >> 4)) * 512 + (k & 15)]) * wr[k * 60];
    }
    __syncthreads();
    fsh[ks * 64 + c] = s;
    __syncthreads();
    if (tid < 60) {
      float lg = fcb[tid];
      #pragma unroll
      for (int i = 0; i < 8; ++i) lg += fsh[i * 64 + tid];
      fsh[512 + tid] = lg;
    }
    __syncthreads();
    if (tid == 0) {
      float mx = -1e30f;
      for (int i = 0; i < 60; ++i) mx = fmaxf(mx, fsh[512 + i]);
      float sm = 0.f;
      for (int i = 0; i < 60; ++i) sm += __expf(fsh[512 + i] - mx);
      fsh[576] = mx + __logf(sm);
    }
    __syncthreads();
    if (tid < 60) out[row * 60 + tid] = fsh[512 + tid] - fsh[576];
    __syncthreads();
  }
}

extern "C" void kernel_launch(void* const* d_in, const int* in_sizes, int n_in,
                              void* d_out, int out_size, void* d_ws, size_t ws_size,
                              hipStream_t stream)
{
  const float* xin = (const float*)d_in[0];   // [5][128][300][30]
  const float* Wx  = (const float*)d_in[1];   // [5][30][1536]
  const float* Wh  = (const float*)d_in[2];   // [5][512][1536]
  const float* bg  = (const float*)d_in[3];   // [5][1536]
  const float* Wxo = (const float*)d_in[4];   // [150][512]
  const float* Who = (const float*)d_in[5];   // [512][512]
  const float* bo  = (const float*)d_in[6];   // [512]
  const float* fcw = (const float*)d_in[7];   // [512][60]
  const float* fcb = (const float*)d_in[8];   // [60]
  float* out = (float*)d_out;                 // [128][60]

  char* ws = (char*)d_ws;
  u16*   Wp    = (u16*)(ws + OFF_WP);
  float* bpack = (float*)(ws + OFF_BP);
  u16*   xb    = (u16*)(ws + OFF_XB);
  u16*   hall  = (u16*)(ws + OFF_H);
  int*   flags = (int*)(ws + OFF_FL);

  hipLaunchKernelGGL(prep, dim3(2688), dim3(256), 0, stream,
                     Wx, Wh, bg, Wxo, Who, bo, Wp, bpack, hall, flags);
  hipLaunchKernelGGL(prep_x, dim3(3600), dim3(256), 0, stream, xin, xb);

  void* args[] = { (void*)&xb, (void*)&Wp, (void*)&bpack, (void*)&hall,
                   (void*)&flags, (void*)&fcw, (void*)&fcb, (void*)&out };
  hipLaunchCooperativeKernel((void*)plstm, dim3(128), dim3(512), args, 0, stream);
}